// Round 1
// baseline (5067.585 us; speedup 1.0000x reference)
//
#include <hip/hip_runtime.h>
#include <math.h>

#define BATCH 32768
#define DIM   512
#define NCODE 8192
#define DECAYF 0.995f
#define OMDF   0.005f
#define EPSF   1e-8f

// ---------------- workspace layout (bytes) ----------------
// 0       : double scal[8]   [0]=n_sum [1]=counts_sum
// 64      : int   counts[NCODE]
// 32832   : float er[NCODE]
// 65600   : int   idxs[BATCH]
// 196672  : float cmax[BATCH*4]
// 720960  : int   cidx[BATCH*4]
// 1245248 : double loss_part[4096]
#define OFF_SCAL   0
#define OFF_COUNTS 64
#define OFF_ER     32832
#define OFF_IDX    65600
#define OFF_CMAX   196672
#define OFF_CIDX   720960
#define OFF_LOSS   1245248
#define NLOSSBLK   4096

__device__ inline void atomAddF(float* p, float v)  { unsafeAtomicAdd(p, v); }
__device__ inline void atomAddD(double* p, double v){ unsafeAtomicAdd(p, v); }

// ---------- K_er: per-code inverse norm er[k] = 1/(||e_k||+eps) ----------
__global__ __launch_bounds__(256) void k_er(const float* __restrict__ emb,
                                            float* __restrict__ er) {
  int row = blockIdx.x * 4 + (threadIdx.x >> 6);
  int l = threadIdx.x & 63;
  const float4* p = (const float4*)(emb + (size_t)row * DIM);
  float4 a = p[l], b = p[l + 64];
  float s = a.x*a.x + a.y*a.y + a.z*a.z + a.w*a.w
          + b.x*b.x + b.y*b.y + b.z*b.z + b.w*b.w;
  #pragma unroll
  for (int off = 32; off > 0; off >>= 1) s += __shfl_down(s, off);
  if (l == 0) er[row] = 1.0f / (sqrtf(s) + EPSF);
}

// ---------- fused similarity GEMM + per-row argmax over a K-chunk ----------
// tile: 64 rows x 128 codes, BK=16, 128 threads, micro 8x8 (2x4 / 2x4 split)
__global__ __launch_bounds__(128, 3) void k_gemm_argmax(
    const float* __restrict__ z, const float* __restrict__ emb,
    const float* __restrict__ er, float* __restrict__ cmax,
    int* __restrict__ cidx) {
  __shared__ float zs[16][64];
  __shared__ float es[16][128];
  const int t  = threadIdx.x;
  const int tx = t & 15;
  const int ty = t >> 4;
  const int row0 = blockIdx.x * 64;
  const int c = blockIdx.y;
  const int k0 = c * 2048;

  float best[8];
  int   bidx[8];
  #pragma unroll
  for (int i = 0; i < 8; i++) { best[i] = -3.0e38f; bidx[i] = 0; }

  for (int kt = 0; kt < 2048; kt += 128) {
    float acc[2][2][4][4];
    #pragma unroll
    for (int a = 0; a < 2; a++)
      #pragma unroll
      for (int b = 0; b < 2; b++)
        #pragma unroll
        for (int i = 0; i < 4; i++)
          #pragma unroll
          for (int j = 0; j < 4; j++) acc[a][b][i][j] = 0.f;

    for (int dt = 0; dt < 512; dt += 16) {
      // stage z tile 64x16 (256 float4 tasks, transposed into zs[d][row])
      #pragma unroll
      for (int it = 0; it < 2; it++) {
        int task = t + it * 128;
        int r = task >> 2;
        int dq = (task & 3) << 2;
        float4 v = *(const float4*)(z + (size_t)(row0 + r) * 512 + dt + dq);
        zs[dq+0][r] = v.x; zs[dq+1][r] = v.y; zs[dq+2][r] = v.z; zs[dq+3][r] = v.w;
      }
      // stage e tile 128x16 (512 float4 tasks)
      #pragma unroll
      for (int it = 0; it < 4; it++) {
        int task = t + it * 128;
        int r = task >> 2;
        int dq = (task & 3) << 2;
        float4 v = *(const float4*)(emb + (size_t)(k0 + kt + r) * 512 + dt + dq);
        es[dq+0][r] = v.x; es[dq+1][r] = v.y; es[dq+2][r] = v.z; es[dq+3][r] = v.w;
      }
      __syncthreads();
      #pragma unroll
      for (int d = 0; d < 16; d++) {
        float4 a0 = *(const float4*)&zs[d][ty * 4];
        float4 a1 = *(const float4*)&zs[d][32 + ty * 4];
        float4 b0 = *(const float4*)&es[d][tx * 4];
        float4 b1 = *(const float4*)&es[d][64 + tx * 4];
        float av[2][4] = {{a0.x,a0.y,a0.z,a0.w},{a1.x,a1.y,a1.z,a1.w}};
        float bv[2][4] = {{b0.x,b0.y,b0.z,b0.w},{b1.x,b1.y,b1.z,b1.w}};
        #pragma unroll
        for (int ig = 0; ig < 2; ig++)
          #pragma unroll
          for (int jg = 0; jg < 2; jg++)
            #pragma unroll
            for (int i = 0; i < 4; i++)
              #pragma unroll
              for (int j = 0; j < 4; j++)
                acc[ig][jg][i][j] = fmaf(av[ig][i], bv[jg][j], acc[ig][jg][i][j]);
      }
      __syncthreads();
    }
    // epilogue: scale by er and update running argmax (first-max tie break)
    #pragma unroll
    for (int jg = 0; jg < 2; jg++)
      #pragma unroll
      for (int j = 0; j < 4; j++) {
        int code = k0 + kt + jg * 64 + tx * 4 + j;
        float e = er[code];
        #pragma unroll
        for (int ig = 0; ig < 2; ig++)
          #pragma unroll
          for (int i = 0; i < 4; i++) {
            float s = acc[ig][jg][i][j] * e;
            int bi = ig * 4 + i;
            if (s > best[bi] || (s == best[bi] && code < bidx[bi])) {
              best[bi] = s; bidx[bi] = code;
            }
          }
      }
  }
  // reduce across the 16 column-lanes of each row group
  #pragma unroll
  for (int off = 1; off < 16; off <<= 1) {
    #pragma unroll
    for (int bi = 0; bi < 8; bi++) {
      float ov = __shfl_xor(best[bi], off);
      int   oi = __shfl_xor(bidx[bi], off);
      if (ov > best[bi] || (ov == best[bi] && oi < bidx[bi])) {
        best[bi] = ov; bidx[bi] = oi;
      }
    }
  }
  if (tx == 0) {
    #pragma unroll
    for (int bi = 0; bi < 8; bi++) {
      int ig = bi >> 2, i = bi & 3;
      int row = row0 + ig * 32 + ty * 4 + i;
      cmax[row * 4 + c] = best[bi];
      cidx[row * 4 + c] = bidx[bi];
    }
  }
}

// ---------- combine 4 chunk candidates per row -> final index ----------
__global__ __launch_bounds__(256) void k_combine(const float* __restrict__ cmax,
                                                 const int* __restrict__ cidx,
                                                 int* __restrict__ idxs,
                                                 float* __restrict__ out3) {
  int b = blockIdx.x * 256 + threadIdx.x;
  float bv = cmax[b * 4];
  int   bi = cidx[b * 4];
  #pragma unroll
  for (int c = 1; c < 4; c++) {
    float v = cmax[b * 4 + c];
    int   i2 = cidx[b * 4 + c];
    if (v > bv || (v == bv && i2 < bi)) { bv = v; bi = i2; }
  }
  idxs[b] = bi;
  out3[b] = (float)bi;
}

// ---------- gather z_q, straight-through out, MSE partials, counts, embed_sum scatter ----------
__global__ __launch_bounds__(256) void k_gather(
    const float* __restrict__ z, const float* __restrict__ emb,
    const int* __restrict__ idxs, float* __restrict__ out0,
    float* __restrict__ embsum, int* __restrict__ counts,
    double* __restrict__ loss_part) {
  __shared__ float red[256];
  int t = threadIdx.x;
  int row = blockIdx.x * 8 + (t >> 5);
  int l = t & 31;
  int d0 = l * 16;
  int idx = idxs[row];
  const float4* zp = (const float4*)(z + (size_t)row * 512 + d0);
  const float4* ep = (const float4*)(emb + (size_t)idx * 512 + d0);
  float4* op = (float4*)(out0 + (size_t)row * 512 + d0);
  float* esump = embsum + (size_t)idx * 512 + d0;
  float ls = 0.f;
  #pragma unroll
  for (int q = 0; q < 4; q++) {
    float4 zv = zp[q];
    float4 ev = ep[q];
    float4 o;
    o.x = zv.x + (ev.x - zv.x);
    o.y = zv.y + (ev.y - zv.y);
    o.z = zv.z + (ev.z - zv.z);
    o.w = zv.w + (ev.w - zv.w);
    op[q] = o;
    float dx = zv.x - ev.x, dy = zv.y - ev.y, dz = zv.z - ev.z, dw = zv.w - ev.w;
    ls += dx*dx + dy*dy + dz*dz + dw*dw;
    atomAddF(esump + q*4 + 0, zv.x);
    atomAddF(esump + q*4 + 1, zv.y);
    atomAddF(esump + q*4 + 2, zv.z);
    atomAddF(esump + q*4 + 3, zv.w);
  }
  if (l == 0) atomicAdd(&counts[idx], 1);
  red[t] = ls;
  __syncthreads();
  for (int off = 128; off > 0; off >>= 1) {
    if (t < off) red[t] += red[t + off];
    __syncthreads();
  }
  if (t == 0) loss_part[blockIdx.x] = (double)red[0];
}

// ---------- cluster-size EMA + partial sums ----------
__global__ __launch_bounds__(256) void k_cluster(const float* __restrict__ cs,
                                                 const int* __restrict__ counts,
                                                 float* __restrict__ out6,
                                                 double* __restrict__ scal) {
  __shared__ double s1[256], s2[256];
  int t = threadIdx.x;
  int i = blockIdx.x * 256 + t;
  float cf = (float)counts[i];
  float ncs = DECAYF * cs[i] + OMDF * cf;
  out6[i] = ncs;
  s1[t] = (double)ncs;
  s2[t] = (double)cf;
  __syncthreads();
  for (int off = 128; off > 0; off >>= 1) {
    if (t < off) { s1[t] += s1[t + off]; s2[t] += s2[t + off]; }
    __syncthreads();
  }
  if (t == 0) { atomAddD(&scal[0], s1[0]); atomAddD(&scal[1], s2[0]); }
}

// ---------- scalars: entropy/diversity/perplexity/vq_loss ----------
__global__ __launch_bounds__(256) void k_scalars(const int* __restrict__ counts,
                                                 const double* __restrict__ scal,
                                                 const double* __restrict__ loss_part,
                                                 float* __restrict__ out1,
                                                 float* __restrict__ out2,
                                                 float* __restrict__ out4) {
  __shared__ double r1[256], r2[256], r3[256];
  int t = threadIdx.x;
  double csum = scal[1];
  double e1 = 0.0, e2 = 0.0, lsum = 0.0;
  for (int i = t; i < NCODE; i += 256) {
    double c = (double)counts[i];
    double p = c / csum;
    e1 += p * log(p + 1e-10);
    double a = c / (double)BATCH;
    e2 += a * log(a + 1e-10);
  }
  for (int i = t; i < NLOSSBLK; i += 256) lsum += loss_part[i];
  r1[t] = e1; r2[t] = e2; r3[t] = lsum;
  __syncthreads();
  for (int off = 128; off > 0; off >>= 1) {
    if (t < off) { r1[t] += r1[t+off]; r2[t] += r2[t+off]; r3[t] += r3[t+off]; }
    __syncthreads();
  }
  if (t == 0) {
    double entropy = -r1[0];
    double maxent = log((double)NCODE);
    double div = (maxent - entropy) / maxent;
    double mse = r3[0] / ((double)BATCH * (double)DIM);
    double vq = 0.3 * mse + mse + 0.001 * div;
    double perp = exp(-r2[0]);
    *out1 = (float)vq;
    *out2 = (float)perp;
    *out4 = (float)div;
  }
}

// ---------- embedding EMA update + renormalize ----------
__global__ __launch_bounds__(128) void k_embed(const float* __restrict__ ea,
                                               const float* __restrict__ embsum,
                                               const float* __restrict__ out6,
                                               const double* __restrict__ scal,
                                               float* __restrict__ out5,
                                               float* __restrict__ out7) {
  __shared__ float red[128];
  int k = blockIdx.x;
  int t = threadIdx.x;
  float n = (float)scal[0];
  float ncs = out6[k];
  float csn = (ncs + EPSF) / (n + (float)NCODE * EPSF) * n;
  size_t base = (size_t)k * 512 + t * 4;
  float v[4];
  float ss = 0.f;
  #pragma unroll
  for (int j = 0; j < 4; j++) {
    float nea = DECAYF * ea[base + j] + OMDF * embsum[base + j];
    v[j] = nea / csn;
    ss += v[j] * v[j];
  }
  red[t] = ss;
  __syncthreads();
  for (int off = 64; off > 0; off >>= 1) {
    if (t < off) red[t] += red[t + off];
    __syncthreads();
  }
  float inv = 1.0f / (sqrtf(red[0]) + EPSF);
  #pragma unroll
  for (int j = 0; j < 4; j++) {
    float nm = v[j] * inv;
    out5[base + j] = nm;
    out7[base + j] = nm * csn;
  }
}

extern "C" void kernel_launch(void* const* d_in, const int* in_sizes, int n_in,
                              void* d_out, int out_size, void* d_ws, size_t ws_size,
                              hipStream_t stream) {
  const float* z   = (const float*)d_in[0];
  const float* emb = (const float*)d_in[1];
  const float* cs  = (const float*)d_in[2];
  const float* ea  = (const float*)d_in[3];

  float* out  = (float*)d_out;
  float* out0 = out;                    // z_q_st        [B*D]
  float* out1 = out + 16777216;         // vq_loss       [1]
  float* out2 = out + 16777217;         // perplexity    [1]
  float* out3 = out + 16777218;         // indices       [B]
  float* out4 = out + 16809986;         // diversity     [1]
  float* out5 = out + 16809987;         // new_embedding [K*D]
  float* out6 = out + 21004291;         // new_cluster   [K]
  float* out7 = out + 21012483;         // final_embed_avg [K*D]  (embed_sum scratch)

  char* ws = (char*)d_ws;
  double* scal      = (double*)(ws + OFF_SCAL);
  int*    counts    = (int*)   (ws + OFF_COUNTS);
  float*  er        = (float*) (ws + OFF_ER);
  int*    idxs      = (int*)   (ws + OFF_IDX);
  float*  cmax      = (float*) (ws + OFF_CMAX);
  int*    cidx      = (int*)   (ws + OFF_CIDX);
  double* loss_part = (double*)(ws + OFF_LOSS);

  // zero scalars + counts; zero embed_sum scratch (out7 region)
  hipMemsetAsync(ws, 0, OFF_ER, stream);
  hipMemsetAsync(out7, 0, (size_t)NCODE * DIM * sizeof(float), stream);

  k_er<<<NCODE / 4, 256, 0, stream>>>(emb, er);
  k_gemm_argmax<<<dim3(BATCH / 64, 4), 128, 0, stream>>>(z, emb, er, cmax, cidx);
  k_combine<<<BATCH / 256, 256, 0, stream>>>(cmax, cidx, idxs, out3);
  k_gather<<<NLOSSBLK, 256, 0, stream>>>(z, emb, idxs, out0, out7, counts, loss_part);
  k_cluster<<<NCODE / 256, 256, 0, stream>>>(cs, counts, out6, scal);
  k_scalars<<<1, 256, 0, stream>>>(counts, scal, loss_part, out1, out2, out4);
  k_embed<<<NCODE, 128, 0, stream>>>(ea, out7, out6, scal, out5, out7);
}

// Round 2
// 1742.467 us; speedup vs baseline: 2.9083x; 2.9083x over previous
//
#include <hip/hip_runtime.h>
#include <math.h>

#define BATCH 32768
#define DIM   512
#define NCODE 8192
#define DECAYF 0.995f
#define OMDF   0.005f
#define EPSF   1e-8f
#define MARGIN 8e-3f
#define MAXFLAG 2048
#define MAXTILE 12

typedef _Float16 half8 __attribute__((ext_vector_type(8)));
typedef _Float16 half4 __attribute__((ext_vector_type(4)));
typedef float f32x4 __attribute__((ext_vector_type(4)));

// ---------------- workspace layout (bytes) ----------------
#define OFF_SCAL   0        // double scal[8]: [0]=n_sum [1]=counts_sum
#define OFF_CNT    64       // int cnt
#define OFF_COUNTS 128      // int counts[NCODE]
#define OFF_ER     32896    // float er[NCODE]
#define OFF_IDX    65664    // int idxs[BATCH]
#define OFF_LOSS   196736   // double loss_part[4096]
#define OFF_FROW   229504   // int frow[MAXFLAG]
#define OFF_NFT    237696   // int nft[MAXFLAG]
#define OFF_FTILE  245888   // int ftile[MAXFLAG*MAXTILE]
#define OFF_RVAL   344192   // float rval[MAXFLAG*MAXTILE]
#define OFF_RIDX   442496   // int ridx[MAXFLAG*MAXTILE]
#define OFF_EH     540800   // _Float16 eh[NCODE*DIM]  (8 MB)
#define NLOSSBLK   4096

__device__ inline void atomAddF(float* p, float v)  { unsafeAtomicAdd(p, v); }
__device__ inline void atomAddD(double* p, double v){ unsafeAtomicAdd(p, v); }

__device__ inline void async_cp16(const _Float16* g, _Float16* l) {
  __builtin_amdgcn_global_load_lds(
      (const __attribute__((address_space(1))) unsigned int*)g,
      (__attribute__((address_space(3))) unsigned int*)l, 16, 0, 0);
}

// ---------- prep: er[k]=1/(||e_k||+eps), eh = fp16(e*er) ----------
__global__ __launch_bounds__(256) void k_prep_e(const float* __restrict__ emb,
                                                float* __restrict__ er,
                                                _Float16* __restrict__ eh) {
  int row = blockIdx.x * 4 + (threadIdx.x >> 6);
  int l = threadIdx.x & 63;
  const float4* p = (const float4*)(emb + (size_t)row * DIM);
  float4 a = p[l], b = p[l + 64];
  float s = a.x*a.x + a.y*a.y + a.z*a.z + a.w*a.w
          + b.x*b.x + b.y*b.y + b.z*b.z + b.w*b.w;
  #pragma unroll
  for (int off = 32; off > 0; off >>= 1) s += __shfl_down(s, off);
  s = __shfl(s, 0);
  float inv = 1.0f / (sqrtf(s) + EPSF);
  if (l == 0) er[row] = inv;
  half4 ha = { (_Float16)(a.x*inv), (_Float16)(a.y*inv), (_Float16)(a.z*inv), (_Float16)(a.w*inv) };
  half4 hb = { (_Float16)(b.x*inv), (_Float16)(b.y*inv), (_Float16)(b.z*inv), (_Float16)(b.w*inv) };
  *(half4*)(eh + (size_t)row * DIM + l * 4) = ha;
  *(half4*)(eh + (size_t)row * DIM + 256 + l * 4) = hb;
}

// ---------- prep: zh = fp16(z) split across out5/out7 regions ----------
__global__ __launch_bounds__(256) void k_prep_z(const float* __restrict__ z,
                                                _Float16* __restrict__ z5,
                                                _Float16* __restrict__ z7) {
  size_t base = ((size_t)blockIdx.x * 256 + threadIdx.x) * 8;
  const float4* zp = (const float4*)(z + base);
  float4 a = zp[0], b = zp[1];
  half8 h = { (_Float16)a.x, (_Float16)a.y, (_Float16)a.z, (_Float16)a.w,
              (_Float16)b.x, (_Float16)b.y, (_Float16)b.z, (_Float16)b.w };
  _Float16* dst = (base < (size_t)16384 * 512) ? (z5 + base)
                                               : (z7 + (base - (size_t)16384 * 512));
  *(half8*)dst = h;
}

// ---------- coarse fp16 MFMA GEMM + per-row top-2 per 128-col tile ----------
__global__ __launch_bounds__(256) void k_coarse(const _Float16* __restrict__ eh,
                                                const _Float16* __restrict__ z5,
                                                const _Float16* __restrict__ z7,
                                                float* __restrict__ c1v,
                                                float* __restrict__ c2v,
                                                int* __restrict__ c1i) {
  __shared__ _Float16 As[4096];  // 128 rows x 32 k
  __shared__ _Float16 Bs[4096];  // 128 codes x 32 k
  __shared__ float ev1[2][128];
  __shared__ float ev2[2][128];
  __shared__ int   ei1[2][128];

  const int t = threadIdx.x, w = t >> 6, lane = t & 63;
  const int quad = lane >> 4, c16 = lane & 15;
  const int row0 = blockIdx.x * 128;
  const int by = blockIdx.y, col0 = by * 128;
  const int m0 = (w & 1) * 64, n0 = (w >> 1) * 64;
  const _Float16* zbase = (row0 < 16384) ? z5 : (z7 - (size_t)16384 * 512);

  const _Float16* ga[2]; const _Float16* gb[2];
  _Float16* la[2]; _Float16* lb[2];
  #pragma unroll
  for (int c = 0; c < 2; c++) {
    int s = (c * 4 + w) * 64 + lane;
    ga[c] = zbase + (size_t)(row0 + (s >> 2)) * 512 + (s & 3) * 8;
    gb[c] = eh + (size_t)(col0 + (s >> 2)) * 512 + (s & 3) * 8;
    la[c] = As + (c * 4 + w) * 512;
    lb[c] = Bs + (c * 4 + w) * 512;
  }

  f32x4 acc[4][4];
  #pragma unroll
  for (int i = 0; i < 4; i++)
    #pragma unroll
    for (int j = 0; j < 4; j++) { acc[i][j][0]=0.f; acc[i][j][1]=0.f; acc[i][j][2]=0.f; acc[i][j][3]=0.f; }

  int offA[4], offB[4];
  #pragma unroll
  for (int i = 0; i < 4; i++) offA[i] = (m0 + i * 16 + c16) * 32 + quad * 8;
  #pragma unroll
  for (int j = 0; j < 4; j++) offB[j] = (n0 + j * 16 + c16) * 32 + quad * 8;

  for (int kk = 0; kk < 16; kk++) {
    #pragma unroll
    for (int c = 0; c < 2; c++) {
      async_cp16(ga[c], la[c]); ga[c] += 32;
      async_cp16(gb[c], lb[c]); gb[c] += 32;
    }
    __syncthreads();
    half8 af[4], bf[4];
    #pragma unroll
    for (int i = 0; i < 4; i++) af[i] = *(const half8*)(As + offA[i]);
    #pragma unroll
    for (int j = 0; j < 4; j++) bf[j] = *(const half8*)(Bs + offB[j]);
    #pragma unroll
    for (int i = 0; i < 4; i++)
      #pragma unroll
      for (int j = 0; j < 4; j++)
        acc[i][j] = __builtin_amdgcn_mfma_f32_16x16x32_f16(af[i], bf[j], acc[i][j], 0, 0, 0);
    __syncthreads();
  }

  // epilogue: per-row top-2 over this block's 128 cols
  const int h = w >> 1;
  #pragma unroll
  for (int i = 0; i < 4; i++) {
    #pragma unroll
    for (int r = 0; r < 4; r++) {
      float v1 = acc[i][0][r];
      int   i1 = col0 + n0 + c16;
      float v2 = -3.0e38f;
      #pragma unroll
      for (int j = 1; j < 4; j++) {
        float v = acc[i][j][r];
        int ix = col0 + n0 + j * 16 + c16;
        if (v > v1) { v2 = fmaxf(v2, v1); v1 = v; i1 = ix; }
        else        { v2 = fmaxf(v2, v); }
      }
      #pragma unroll
      for (int m = 1; m < 16; m <<= 1) {
        float o1 = __shfl_xor(v1, m);
        float o2 = __shfl_xor(v2, m);
        int   oi = __shfl_xor(i1, m);
        if (o1 > v1 || (o1 == v1 && oi < i1)) { v2 = fmaxf(v1, o2); v1 = o1; i1 = oi; }
        else                                  { v2 = fmaxf(v2, o1); }
      }
      if (c16 == 0) {
        int rl = (w & 1) * 64 + i * 16 + quad * 4 + r;
        ev1[h][rl] = v1; ev2[h][rl] = v2; ei1[h][rl] = i1;
      }
    }
  }
  __syncthreads();
  if (t < 128) {
    float a1 = ev1[0][t], a2 = ev2[0][t]; int ai = ei1[0][t];
    float b1 = ev1[1][t], b2 = ev2[1][t]; int bi = ei1[1][t];
    float v1, v2; int i1;
    if (b1 > a1 || (b1 == a1 && bi < ai)) { v1 = b1; i1 = bi; v2 = fmaxf(a1, b2); }
    else                                  { v1 = a1; i1 = ai; v2 = fmaxf(a2, b1); }
    size_t o = (size_t)by * BATCH + row0 + t;
    c1v[o] = v1; c2v[o] = v2; c1i[o] = i1;
  }
}

// ---------- combine 64 tiles/row, margin test, flag list ----------
__global__ __launch_bounds__(256) void k_combine(const float* __restrict__ c1v,
                                                 const float* __restrict__ c2v,
                                                 const int* __restrict__ c1i,
                                                 int* __restrict__ idxs,
                                                 float* __restrict__ out3,
                                                 int* __restrict__ cnt,
                                                 int* __restrict__ frow,
                                                 int* __restrict__ nft,
                                                 int* __restrict__ ftile) {
  int row = blockIdx.x * 256 + threadIdx.x;
  float v1 = -3.0e38f, v2 = -3.0e38f; int i1 = 0;
  for (int ti = 0; ti < 64; ti++) {
    size_t o = (size_t)ti * BATCH + row;
    float a = c1v[o]; float a2 = c2v[o]; int ai = c1i[o];
    if (a > v1 || (a == v1 && ai < i1)) { v2 = fmaxf(v1, a2); v1 = a; i1 = ai; }
    else                                { v2 = fmaxf(v2, a); }
  }
  idxs[row] = i1;
  out3[row] = (float)i1;
  if (v1 - v2 < MARGIN) {
    int fid = atomicAdd(cnt, 1);
    if (fid < MAXFLAG) {
      frow[fid] = row;
      int jj = 0;
      for (int ti = 0; ti < 64; ti++) {
        if (c1v[(size_t)ti * BATCH + row] >= v1 - MARGIN && jj < MAXTILE)
          ftile[fid * MAXTILE + jj++] = ti;
      }
      nft[fid] = jj;
    }
  }
}

// ---------- exact fp32 refine of qualifying tiles for flagged rows ----------
__global__ __launch_bounds__(256) void k_refine(const float* __restrict__ z,
                                                const float* __restrict__ emb,
                                                const float* __restrict__ er,
                                                const int* __restrict__ cnt,
                                                const int* __restrict__ frow,
                                                const int* __restrict__ nft,
                                                const int* __restrict__ ftile,
                                                float* __restrict__ rval,
                                                int* __restrict__ ridx) {
  __shared__ float zl[512];
  __shared__ float rv[128];
  __shared__ int   ri[128];
  int fid = blockIdx.x;
  int m = cnt[0]; if (m > MAXFLAG) m = MAXFLAG;
  if (fid >= m) return;
  int t = threadIdx.x;
  int row = frow[fid];
  if (t < 128) ((float4*)zl)[t] = *(const float4*)(z + (size_t)row * 512 + t * 4);
  __syncthreads();
  int n = nft[fid];
  for (int jj = 0; jj < n; jj++) {
    int ti = ftile[fid * MAXTILE + jj];
    if (t < 128) {
      int code = ti * 128 + t;
      const float4* ep = (const float4*)(emb + (size_t)code * 512);
      const float4* zp = (const float4*)zl;
      float a0 = 0.f, a1 = 0.f, a2 = 0.f, a3 = 0.f;
      #pragma unroll 8
      for (int d = 0; d < 128; d++) {
        float4 e4 = ep[d]; float4 z4 = zp[d];
        a0 = fmaf(e4.x, z4.x, a0); a1 = fmaf(e4.y, z4.y, a1);
        a2 = fmaf(e4.z, z4.z, a2); a3 = fmaf(e4.w, z4.w, a3);
      }
      rv[t] = ((a0 + a1) + (a2 + a3)) * er[code];
      ri[t] = code;
    }
    __syncthreads();
    for (int off = 64; off > 0; off >>= 1) {
      if (t < off) {
        if (rv[t + off] > rv[t] || (rv[t + off] == rv[t] && ri[t + off] < ri[t])) {
          rv[t] = rv[t + off]; ri[t] = ri[t + off];
        }
      }
      __syncthreads();
    }
    if (t == 0) { rval[fid * MAXTILE + jj] = rv[0]; ridx[fid * MAXTILE + jj] = ri[0]; }
    __syncthreads();
  }
}

// ---------- merge refine results -> final index for flagged rows ----------
__global__ __launch_bounds__(256) void k_merge(const int* __restrict__ cnt,
                                               const int* __restrict__ frow,
                                               const int* __restrict__ nft,
                                               const float* __restrict__ rval,
                                               const int* __restrict__ ridx,
                                               int* __restrict__ idxs,
                                               float* __restrict__ out3) {
  int fid = blockIdx.x * 256 + threadIdx.x;
  int m = cnt[0]; if (m > MAXFLAG) m = MAXFLAG;
  if (fid >= m) return;
  int n = nft[fid];
  float bv = rval[fid * MAXTILE]; int bi = ridx[fid * MAXTILE];
  for (int jj = 1; jj < n; jj++) {
    float v = rval[fid * MAXTILE + jj]; int ix = ridx[fid * MAXTILE + jj];
    if (v > bv || (v == bv && ix < bi)) { bv = v; bi = ix; }
  }
  int row = frow[fid];
  idxs[row] = bi;
  out3[row] = (float)bi;
}

// ---------- gather z_q, ST out, MSE partials, counts, embed_sum scatter ----------
__global__ __launch_bounds__(256) void k_gather(
    const float* __restrict__ z, const float* __restrict__ emb,
    const int* __restrict__ idxs, float* __restrict__ out0,
    float* __restrict__ embsum, int* __restrict__ counts,
    double* __restrict__ loss_part) {
  __shared__ float red[256];
  int t = threadIdx.x;
  int row = blockIdx.x * 8 + (t >> 5);
  int l = t & 31;
  int d0 = l * 16;
  int idx = idxs[row];
  const float4* zp = (const float4*)(z + (size_t)row * 512 + d0);
  const float4* ep = (const float4*)(emb + (size_t)idx * 512 + d0);
  float4* op = (float4*)(out0 + (size_t)row * 512 + d0);
  float* esump = embsum + (size_t)idx * 512 + d0;
  float ls = 0.f;
  #pragma unroll
  for (int q = 0; q < 4; q++) {
    float4 zv = zp[q];
    float4 ev = ep[q];
    op[q] = ev;  // z + (z_q - z) == z_q
    float dx = zv.x - ev.x, dy = zv.y - ev.y, dz = zv.z - ev.z, dw = zv.w - ev.w;
    ls += dx*dx + dy*dy + dz*dz + dw*dw;
    atomAddF(esump + q*4 + 0, zv.x);
    atomAddF(esump + q*4 + 1, zv.y);
    atomAddF(esump + q*4 + 2, zv.z);
    atomAddF(esump + q*4 + 3, zv.w);
  }
  if (l == 0) atomicAdd(&counts[idx], 1);
  red[t] = ls;
  __syncthreads();
  for (int off = 128; off > 0; off >>= 1) {
    if (t < off) red[t] += red[t + off];
    __syncthreads();
  }
  if (t == 0) loss_part[blockIdx.x] = (double)red[0];
}

// ---------- cluster-size EMA + partial sums ----------
__global__ __launch_bounds__(256) void k_cluster(const float* __restrict__ cs,
                                                 const int* __restrict__ counts,
                                                 float* __restrict__ out6,
                                                 double* __restrict__ scal) {
  __shared__ double s1[256], s2[256];
  int t = threadIdx.x;
  int i = blockIdx.x * 256 + t;
  float cf = (float)counts[i];
  float ncs = DECAYF * cs[i] + OMDF * cf;
  out6[i] = ncs;
  s1[t] = (double)ncs;
  s2[t] = (double)cf;
  __syncthreads();
  for (int off = 128; off > 0; off >>= 1) {
    if (t < off) { s1[t] += s1[t + off]; s2[t] += s2[t + off]; }
    __syncthreads();
  }
  if (t == 0) { atomAddD(&scal[0], s1[0]); atomAddD(&scal[1], s2[0]); }
}

// ---------- scalars ----------
__global__ __launch_bounds__(256) void k_scalars(const int* __restrict__ counts,
                                                 const double* __restrict__ scal,
                                                 const double* __restrict__ loss_part,
                                                 float* __restrict__ out1,
                                                 float* __restrict__ out2,
                                                 float* __restrict__ out4) {
  __shared__ double r1[256], r2[256], r3[256];
  int t = threadIdx.x;
  double csum = scal[1];
  double e1 = 0.0, e2 = 0.0, lsum = 0.0;
  for (int i = t; i < NCODE; i += 256) {
    double c = (double)counts[i];
    double p = c / csum;
    e1 += p * log(p + 1e-10);
    double a = c / (double)BATCH;
    e2 += a * log(a + 1e-10);
  }
  for (int i = t; i < NLOSSBLK; i += 256) lsum += loss_part[i];
  r1[t] = e1; r2[t] = e2; r3[t] = lsum;
  __syncthreads();
  for (int off = 128; off > 0; off >>= 1) {
    if (t < off) { r1[t] += r1[t+off]; r2[t] += r2[t+off]; r3[t] += r3[t+off]; }
    __syncthreads();
  }
  if (t == 0) {
    double entropy = -r1[0];
    double maxent = log((double)NCODE);
    double div = (maxent - entropy) / maxent;
    double mse = r3[0] / ((double)BATCH * (double)DIM);
    double vq = 0.3 * mse + mse + 0.001 * div;
    double perp = exp(-r2[0]);
    *out1 = (float)vq;
    *out2 = (float)perp;
    *out4 = (float)div;
  }
}

// ---------- embedding EMA + renormalize ----------
__global__ __launch_bounds__(128) void k_embed(const float* __restrict__ ea,
                                               const float* __restrict__ embsum,
                                               const float* __restrict__ out6,
                                               const double* __restrict__ scal,
                                               float* __restrict__ out5,
                                               float* __restrict__ out7) {
  __shared__ float red[128];
  int k = blockIdx.x;
  int t = threadIdx.x;
  float n = (float)scal[0];
  float ncs = out6[k];
  float csn = (ncs + EPSF) / (n + (float)NCODE * EPSF) * n;
  size_t base = (size_t)k * 512 + t * 4;
  float v[4];
  float ss = 0.f;
  #pragma unroll
  for (int j = 0; j < 4; j++) {
    float nea = DECAYF * ea[base + j] + OMDF * embsum[base + j];
    v[j] = nea / csn;
    ss += v[j] * v[j];
  }
  red[t] = ss;
  __syncthreads();
  for (int off = 64; off > 0; off >>= 1) {
    if (t < off) red[t] += red[t + off];
    __syncthreads();
  }
  float inv = 1.0f / (sqrtf(red[0]) + EPSF);
  #pragma unroll
  for (int j = 0; j < 4; j++) {
    float nm = v[j] * inv;
    out5[base + j] = nm;
    out7[base + j] = nm * csn;
  }
}

extern "C" void kernel_launch(void* const* d_in, const int* in_sizes, int n_in,
                              void* d_out, int out_size, void* d_ws, size_t ws_size,
                              hipStream_t stream) {
  const float* z   = (const float*)d_in[0];
  const float* emb = (const float*)d_in[1];
  const float* cs  = (const float*)d_in[2];
  const float* ea  = (const float*)d_in[3];

  float* out  = (float*)d_out;
  float* out0 = out;                    // z_q_st        [B*D]
  float* out1 = out + 16777216;         // vq_loss       [1]
  float* out2 = out + 16777217;         // perplexity    [1]
  float* out3 = out + 16777218;         // indices       [B]
  float* out4 = out + 16809986;         // diversity     [1]
  float* out5 = out + 16809987;         // new_embedding [K*D]
  float* out6 = out + 21004291;         // new_cluster   [K]
  float* out7 = out + 21012483;         // final_embed_avg [K*D]

  char* ws = (char*)d_ws;
  double* scal      = (double*)(ws + OFF_SCAL);
  int*    cnt       = (int*)   (ws + OFF_CNT);
  int*    counts    = (int*)   (ws + OFF_COUNTS);
  float*  er        = (float*) (ws + OFF_ER);
  int*    idxs      = (int*)   (ws + OFF_IDX);
  double* loss_part = (double*)(ws + OFF_LOSS);
  int*    frow      = (int*)   (ws + OFF_FROW);
  int*    nft       = (int*)   (ws + OFF_NFT);
  int*    ftile     = (int*)   (ws + OFF_FTILE);
  float*  rval      = (float*) (ws + OFF_RVAL);
  int*    ridx      = (int*)   (ws + OFF_RIDX);
  _Float16* eh      = (_Float16*)(ws + OFF_EH);

  // zh (fp16 z) overlays out5+out7 (dead until k_embed); coarse candidate
  // arrays overlay out0 (dead until k_gather rewrites it)
  _Float16* zh5 = (_Float16*)out5;   // rows 0..16383
  _Float16* zh7 = (_Float16*)out7;   // rows 16384..32767
  float* c1v = out0;                 // [64][BATCH]
  float* c2v = out0 + (size_t)64 * BATCH;
  int*   c1i = (int*)(out0 + (size_t)128 * BATCH);

  hipMemsetAsync(ws, 0, OFF_ER, stream);  // scal, cnt, counts

  k_prep_e<<<NCODE / 4, 256, 0, stream>>>(emb, er, eh);
  k_prep_z<<<8192, 256, 0, stream>>>(z, zh5, zh7);
  k_coarse<<<dim3(BATCH / 128, NCODE / 128), 256, 0, stream>>>(eh, zh5, zh7, c1v, c2v, c1i);
  k_combine<<<BATCH / 256, 256, 0, stream>>>(c1v, c2v, c1i, idxs, out3, cnt, frow, nft, ftile);
  k_refine<<<MAXFLAG, 256, 0, stream>>>(z, emb, er, cnt, frow, nft, ftile, rval, ridx);
  k_merge<<<MAXFLAG / 256, 256, 0, stream>>>(cnt, frow, nft, rval, ridx, idxs, out3);

  hipMemsetAsync(out7, 0, (size_t)NCODE * DIM * sizeof(float), stream);  // embsum
  k_gather<<<NLOSSBLK, 256, 0, stream>>>(z, emb, idxs, out0, out7, counts, loss_part);
  k_cluster<<<NCODE / 256, 256, 0, stream>>>(cs, counts, out6, scal);
  k_scalars<<<1, 256, 0, stream>>>(counts, scal, loss_part, out1, out2, out4);
  k_embed<<<NCODE, 128, 0, stream>>>(ea, out7, out6, scal, out5, out7);
}

// Round 3
// 872.660 us; speedup vs baseline: 5.8071x; 1.9967x over previous
//
#include <hip/hip_runtime.h>
#include <math.h>

#define BATCH 32768
#define DIM   512
#define NCODE 8192
#define DECAYF 0.995f
#define OMDF   0.005f
#define EPSF   1e-8f
#define MARGIN 8e-3f
#define MAXFLAG 2048
#define MAXTILE 12

typedef _Float16 half8 __attribute__((ext_vector_type(8)));
typedef _Float16 half4 __attribute__((ext_vector_type(4)));
typedef float f32x4 __attribute__((ext_vector_type(4)));

// ---------------- workspace layout (bytes) ----------------
#define OFF_SCAL   0        // double scal[8]: [0]=n_sum [1]=counts_sum
#define OFF_CNT    64       // int cnt
#define OFF_COUNTS 128      // int counts[NCODE]
#define OFF_ER     32896    // float er[NCODE]
#define OFF_IDX    65664    // int idxs[BATCH]
#define OFF_LOSS   196736   // double loss_part[4096]
#define OFF_FROW   229504   // int frow[MAXFLAG]
#define OFF_NFT    237696   // int nft[MAXFLAG]
#define OFF_FTILE  245888   // int ftile[MAXFLAG*MAXTILE]
#define OFF_RVAL   344192   // float rval[MAXFLAG*MAXTILE]
#define OFF_RIDX   442496   // int ridx[MAXFLAG*MAXTILE]
#define OFF_EH     540800   // _Float16 eh[NCODE*DIM]  (8 MB)
#define NLOSSBLK   4096

__device__ inline void atomAddD(double* p, double v){ unsafeAtomicAdd(p, v); }

__device__ inline void async_cp16(const _Float16* g, _Float16* l) {
  __builtin_amdgcn_global_load_lds(
      (const __attribute__((address_space(1))) unsigned int*)g,
      (__attribute__((address_space(3))) unsigned int*)l, 16, 0, 0);
}

// ---------- prep: er[k]=1/(||e_k||+eps), eh = fp16(e*er) ----------
__global__ __launch_bounds__(256) void k_prep_e(const float* __restrict__ emb,
                                                float* __restrict__ er,
                                                _Float16* __restrict__ eh) {
  int row = blockIdx.x * 4 + (threadIdx.x >> 6);
  int l = threadIdx.x & 63;
  const float4* p = (const float4*)(emb + (size_t)row * DIM);
  float4 a = p[l], b = p[l + 64];
  float s = a.x*a.x + a.y*a.y + a.z*a.z + a.w*a.w
          + b.x*b.x + b.y*b.y + b.z*b.z + b.w*b.w;
  #pragma unroll
  for (int off = 32; off > 0; off >>= 1) s += __shfl_down(s, off);
  s = __shfl(s, 0);
  float inv = 1.0f / (sqrtf(s) + EPSF);
  if (l == 0) er[row] = inv;
  half4 ha = { (_Float16)(a.x*inv), (_Float16)(a.y*inv), (_Float16)(a.z*inv), (_Float16)(a.w*inv) };
  half4 hb = { (_Float16)(b.x*inv), (_Float16)(b.y*inv), (_Float16)(b.z*inv), (_Float16)(b.w*inv) };
  *(half4*)(eh + (size_t)row * DIM + l * 4) = ha;
  *(half4*)(eh + (size_t)row * DIM + 256 + l * 4) = hb;
}

// ---------- prep: zh = fp16(z) split across out5/out7 regions ----------
__global__ __launch_bounds__(256) void k_prep_z(const float* __restrict__ z,
                                                _Float16* __restrict__ z5,
                                                _Float16* __restrict__ z7) {
  size_t base = ((size_t)blockIdx.x * 256 + threadIdx.x) * 8;
  const float4* zp = (const float4*)(z + base);
  float4 a = zp[0], b = zp[1];
  half8 h = { (_Float16)a.x, (_Float16)a.y, (_Float16)a.z, (_Float16)a.w,
              (_Float16)b.x, (_Float16)b.y, (_Float16)b.z, (_Float16)b.w };
  _Float16* dst = (base < (size_t)16384 * 512) ? (z5 + base)
                                               : (z7 + (base - (size_t)16384 * 512));
  *(half8*)dst = h;
}

// ---------- coarse fp16 MFMA GEMM + per-row top-2 per 128-col tile ----------
__global__ __launch_bounds__(256) void k_coarse(const _Float16* __restrict__ eh,
                                                const _Float16* __restrict__ z5,
                                                const _Float16* __restrict__ z7,
                                                float* __restrict__ c1v,
                                                float* __restrict__ c2v,
                                                int* __restrict__ c1i) {
  __shared__ _Float16 As[4096];  // 128 rows x 32 k
  __shared__ _Float16 Bs[4096];  // 128 codes x 32 k
  __shared__ float ev1[2][128];
  __shared__ float ev2[2][128];
  __shared__ int   ei1[2][128];

  const int t = threadIdx.x, w = t >> 6, lane = t & 63;
  const int quad = lane >> 4, c16 = lane & 15;
  const int row0 = blockIdx.x * 128;
  const int by = blockIdx.y, col0 = by * 128;
  const int m0 = (w & 1) * 64, n0 = (w >> 1) * 64;
  const _Float16* zbase = (row0 < 16384) ? z5 : (z7 - (size_t)16384 * 512);

  const _Float16* ga[2]; const _Float16* gb[2];
  _Float16* la[2]; _Float16* lb[2];
  #pragma unroll
  for (int c = 0; c < 2; c++) {
    int s = (c * 4 + w) * 64 + lane;
    ga[c] = zbase + (size_t)(row0 + (s >> 2)) * 512 + (s & 3) * 8;
    gb[c] = eh + (size_t)(col0 + (s >> 2)) * 512 + (s & 3) * 8;
    la[c] = As + (c * 4 + w) * 512;
    lb[c] = Bs + (c * 4 + w) * 512;
  }

  f32x4 acc[4][4];
  #pragma unroll
  for (int i = 0; i < 4; i++)
    #pragma unroll
    for (int j = 0; j < 4; j++) { acc[i][j][0]=0.f; acc[i][j][1]=0.f; acc[i][j][2]=0.f; acc[i][j][3]=0.f; }

  int offA[4], offB[4];
  #pragma unroll
  for (int i = 0; i < 4; i++) offA[i] = (m0 + i * 16 + c16) * 32 + quad * 8;
  #pragma unroll
  for (int j = 0; j < 4; j++) offB[j] = (n0 + j * 16 + c16) * 32 + quad * 8;

  for (int kk = 0; kk < 16; kk++) {
    #pragma unroll
    for (int c = 0; c < 2; c++) {
      async_cp16(ga[c], la[c]); ga[c] += 32;
      async_cp16(gb[c], lb[c]); gb[c] += 32;
    }
    __syncthreads();
    half8 af[4], bf[4];
    #pragma unroll
    for (int i = 0; i < 4; i++) af[i] = *(const half8*)(As + offA[i]);
    #pragma unroll
    for (int j = 0; j < 4; j++) bf[j] = *(const half8*)(Bs + offB[j]);
    #pragma unroll
    for (int i = 0; i < 4; i++)
      #pragma unroll
      for (int j = 0; j < 4; j++)
        acc[i][j] = __builtin_amdgcn_mfma_f32_16x16x32_f16(af[i], bf[j], acc[i][j], 0, 0, 0);
    __syncthreads();
  }

  // epilogue: per-row top-2 over this block's 128 cols
  const int h = w >> 1;
  #pragma unroll
  for (int i = 0; i < 4; i++) {
    #pragma unroll
    for (int r = 0; r < 4; r++) {
      float v1 = acc[i][0][r];
      int   i1 = col0 + n0 + c16;
      float v2 = -3.0e38f;
      #pragma unroll
      for (int j = 1; j < 4; j++) {
        float v = acc[i][j][r];
        int ix = col0 + n0 + j * 16 + c16;
        if (v > v1) { v2 = fmaxf(v2, v1); v1 = v; i1 = ix; }
        else        { v2 = fmaxf(v2, v); }
      }
      #pragma unroll
      for (int m = 1; m < 16; m <<= 1) {
        float o1 = __shfl_xor(v1, m);
        float o2 = __shfl_xor(v2, m);
        int   oi = __shfl_xor(i1, m);
        if (o1 > v1 || (o1 == v1 && oi < i1)) { v2 = fmaxf(v1, o2); v1 = o1; i1 = oi; }
        else                                  { v2 = fmaxf(v2, o1); }
      }
      if (c16 == 0) {
        int rl = (w & 1) * 64 + i * 16 + quad * 4 + r;
        ev1[h][rl] = v1; ev2[h][rl] = v2; ei1[h][rl] = i1;
      }
    }
  }
  __syncthreads();
  if (t < 128) {
    float a1 = ev1[0][t], a2 = ev2[0][t]; int ai = ei1[0][t];
    float b1 = ev1[1][t], b2 = ev2[1][t]; int bi = ei1[1][t];
    float v1, v2; int i1;
    if (b1 > a1 || (b1 == a1 && bi < ai)) { v1 = b1; i1 = bi; v2 = fmaxf(a1, b2); }
    else                                  { v1 = a1; i1 = ai; v2 = fmaxf(a2, b1); }
    size_t o = (size_t)by * BATCH + row0 + t;
    c1v[o] = v1; c2v[o] = v2; c1i[o] = i1;
  }
}

// ---------- combine 64 tiles/row, margin test, flag list ----------
__global__ __launch_bounds__(256) void k_combine(const float* __restrict__ c1v,
                                                 const float* __restrict__ c2v,
                                                 const int* __restrict__ c1i,
                                                 int* __restrict__ idxs,
                                                 float* __restrict__ out3,
                                                 int* __restrict__ cnt,
                                                 int* __restrict__ frow,
                                                 int* __restrict__ nft,
                                                 int* __restrict__ ftile) {
  int row = blockIdx.x * 256 + threadIdx.x;
  float v1 = -3.0e38f, v2 = -3.0e38f; int i1 = 0;
  for (int ti = 0; ti < 64; ti++) {
    size_t o = (size_t)ti * BATCH + row;
    float a = c1v[o]; float a2 = c2v[o]; int ai = c1i[o];
    if (a > v1 || (a == v1 && ai < i1)) { v2 = fmaxf(v1, a2); v1 = a; i1 = ai; }
    else                                { v2 = fmaxf(v2, a); }
  }
  idxs[row] = i1;
  out3[row] = (float)i1;
  if (v1 - v2 < MARGIN) {
    int fid = atomicAdd(cnt, 1);
    if (fid < MAXFLAG) {
      frow[fid] = row;
      int jj = 0;
      for (int ti = 0; ti < 64; ti++) {
        if (c1v[(size_t)ti * BATCH + row] >= v1 - MARGIN && jj < MAXTILE)
          ftile[fid * MAXTILE + jj++] = ti;
      }
      nft[fid] = jj;
    }
  }
}

// ---------- exact fp32 refine of qualifying tiles for flagged rows ----------
__global__ __launch_bounds__(256) void k_refine(const float* __restrict__ z,
                                                const float* __restrict__ emb,
                                                const float* __restrict__ er,
                                                const int* __restrict__ cnt,
                                                const int* __restrict__ frow,
                                                const int* __restrict__ nft,
                                                const int* __restrict__ ftile,
                                                float* __restrict__ rval,
                                                int* __restrict__ ridx) {
  __shared__ float zl[512];
  __shared__ float rv[128];
  __shared__ int   ri[128];
  int fid = blockIdx.x;
  int m = cnt[0]; if (m > MAXFLAG) m = MAXFLAG;
  if (fid >= m) return;
  int t = threadIdx.x;
  int row = frow[fid];
  if (t < 128) ((float4*)zl)[t] = *(const float4*)(z + (size_t)row * 512 + t * 4);
  __syncthreads();
  int n = nft[fid];
  for (int jj = 0; jj < n; jj++) {
    int ti = ftile[fid * MAXTILE + jj];
    if (t < 128) {
      int code = ti * 128 + t;
      const float4* ep = (const float4*)(emb + (size_t)code * 512);
      const float4* zp = (const float4*)zl;
      float a0 = 0.f, a1 = 0.f, a2 = 0.f, a3 = 0.f;
      #pragma unroll 8
      for (int d = 0; d < 128; d++) {
        float4 e4 = ep[d]; float4 z4 = zp[d];
        a0 = fmaf(e4.x, z4.x, a0); a1 = fmaf(e4.y, z4.y, a1);
        a2 = fmaf(e4.z, z4.z, a2); a3 = fmaf(e4.w, z4.w, a3);
      }
      rv[t] = ((a0 + a1) + (a2 + a3)) * er[code];
      ri[t] = code;
    }
    __syncthreads();
    for (int off = 64; off > 0; off >>= 1) {
      if (t < off) {
        if (rv[t + off] > rv[t] || (rv[t + off] == rv[t] && ri[t + off] < ri[t])) {
          rv[t] = rv[t + off]; ri[t] = ri[t + off];
        }
      }
      __syncthreads();
    }
    if (t == 0) { rval[fid * MAXTILE + jj] = rv[0]; ridx[fid * MAXTILE + jj] = ri[0]; }
    __syncthreads();
  }
}

// ---------- merge refine results -> final index for flagged rows ----------
__global__ __launch_bounds__(256) void k_merge(const int* __restrict__ cnt,
                                               const int* __restrict__ frow,
                                               const int* __restrict__ nft,
                                               const float* __restrict__ rval,
                                               const int* __restrict__ ridx,
                                               int* __restrict__ idxs,
                                               float* __restrict__ out3) {
  int fid = blockIdx.x * 256 + threadIdx.x;
  int m = cnt[0]; if (m > MAXFLAG) m = MAXFLAG;
  if (fid >= m) return;
  int n = nft[fid];
  float bv = rval[fid * MAXTILE]; int bi = ridx[fid * MAXTILE];
  for (int jj = 1; jj < n; jj++) {
    float v = rval[fid * MAXTILE + jj]; int ix = ridx[fid * MAXTILE + jj];
    if (v > bv || (v == bv && ix < bi)) { bv = v; bi = ix; }
  }
  int row = frow[fid];
  idxs[row] = bi;
  out3[row] = (float)bi;
}

// ---------- counts from final indices (32768 int atomics) ----------
__global__ __launch_bounds__(256) void k_count(const int* __restrict__ idxs,
                                               int* __restrict__ counts) {
  int row = blockIdx.x * 256 + threadIdx.x;
  atomicAdd(&counts[idxs[row]], 1);
}

// ---------- exclusive prefix sum of counts -> offs, curs ----------
__global__ __launch_bounds__(256) void k_prefix(const int* __restrict__ counts,
                                                int* __restrict__ offs,
                                                int* __restrict__ curs) {
  __shared__ int ls[256];
  int t = threadIdx.x;
  int base = t * 32;
  int local[32];
  int s = 0;
  #pragma unroll
  for (int i = 0; i < 32; i++) { local[i] = s; s += counts[base + i]; }
  ls[t] = s;
  __syncthreads();
  for (int off = 1; off < 256; off <<= 1) {
    int add = (t >= off) ? ls[t - off] : 0;
    __syncthreads();
    ls[t] += add;
    __syncthreads();
  }
  int pre = (t == 0) ? 0 : ls[t - 1];
  #pragma unroll
  for (int i = 0; i < 32; i++) {
    int o = pre + local[i];
    offs[base + i] = o;
    curs[base + i] = o;
  }
  if (t == 255) offs[NCODE] = pre + s;
}

// ---------- scatter row ids into per-code buckets ----------
__global__ __launch_bounds__(256) void k_bucket(const int* __restrict__ idxs,
                                                int* __restrict__ curs,
                                                int* __restrict__ bucket) {
  int row = blockIdx.x * 256 + threadIdx.x;
  int idx = idxs[row];
  int pos = atomicAdd(&curs[idx], 1);
  bucket[pos] = row;
}

// ---------- cluster-size EMA + partial sums ----------
__global__ __launch_bounds__(256) void k_cluster(const float* __restrict__ cs,
                                                 const int* __restrict__ counts,
                                                 float* __restrict__ out6,
                                                 double* __restrict__ scal) {
  __shared__ double s1[256], s2[256];
  int t = threadIdx.x;
  int i = blockIdx.x * 256 + t;
  float cf = (float)counts[i];
  float ncs = DECAYF * cs[i] + OMDF * cf;
  out6[i] = ncs;
  s1[t] = (double)ncs;
  s2[t] = (double)cf;
  __syncthreads();
  for (int off = 128; off > 0; off >>= 1) {
    if (t < off) { s1[t] += s1[t + off]; s2[t] += s2[t + off]; }
    __syncthreads();
  }
  if (t == 0) { atomAddD(&scal[0], s1[0]); atomAddD(&scal[1], s2[0]); }
}

// ---------- embedding: bucket-sum + EMA + renormalize (no atomics) ----------
__global__ __launch_bounds__(128) void k_embed(const float* __restrict__ z,
                                               const float* __restrict__ ea,
                                               const int* __restrict__ offs,
                                               const int* __restrict__ bucket,
                                               const float* __restrict__ out6,
                                               const double* __restrict__ scal,
                                               float* __restrict__ out5,
                                               float* __restrict__ out7) {
  __shared__ float red[128];
  int k = blockIdx.x;
  int t = threadIdx.x;
  int beg = offs[k], end = offs[k + 1];
  float s0 = 0.f, s1 = 0.f, s2 = 0.f, s3 = 0.f;
  for (int j = beg; j < end; j++) {
    int r = bucket[j];
    float4 zv = *(const float4*)(z + (size_t)r * 512 + t * 4);
    s0 += zv.x; s1 += zv.y; s2 += zv.z; s3 += zv.w;
  }
  float n = (float)scal[0];
  float ncs = out6[k];
  float csn = (ncs + EPSF) / (n + (float)NCODE * EPSF) * n;
  size_t base = (size_t)k * 512 + t * 4;
  float4 eav = *(const float4*)(ea + base);
  float v[4];
  v[0] = (DECAYF * eav.x + OMDF * s0) / csn;
  v[1] = (DECAYF * eav.y + OMDF * s1) / csn;
  v[2] = (DECAYF * eav.z + OMDF * s2) / csn;
  v[3] = (DECAYF * eav.w + OMDF * s3) / csn;
  float ss = v[0]*v[0] + v[1]*v[1] + v[2]*v[2] + v[3]*v[3];
  red[t] = ss;
  __syncthreads();
  for (int off = 64; off > 0; off >>= 1) {
    if (t < off) red[t] += red[t + off];
    __syncthreads();
  }
  float inv = 1.0f / (sqrtf(red[0]) + EPSF);
  #pragma unroll
  for (int j = 0; j < 4; j++) {
    float nm = v[j] * inv;
    out5[base + j] = nm;
    out7[base + j] = nm * csn;
  }
}

// ---------- gather z_q -> out0 + MSE partials (no atomics) ----------
__global__ __launch_bounds__(256) void k_gather(
    const float* __restrict__ z, const float* __restrict__ emb,
    const int* __restrict__ idxs, float* __restrict__ out0,
    double* __restrict__ loss_part) {
  __shared__ float red[256];
  int t = threadIdx.x;
  int row = blockIdx.x * 8 + (t >> 5);
  int l = t & 31;
  int d0 = l * 16;
  int idx = idxs[row];
  const float4* zp = (const float4*)(z + (size_t)row * 512 + d0);
  const float4* ep = (const float4*)(emb + (size_t)idx * 512 + d0);
  float4* op = (float4*)(out0 + (size_t)row * 512 + d0);
  float ls = 0.f;
  #pragma unroll
  for (int q = 0; q < 4; q++) {
    float4 zv = zp[q];
    float4 ev = ep[q];
    op[q] = ev;  // z + (z_q - z) == z_q
    float dx = zv.x - ev.x, dy = zv.y - ev.y, dz = zv.z - ev.z, dw = zv.w - ev.w;
    ls += dx*dx + dy*dy + dz*dz + dw*dw;
  }
  red[t] = ls;
  __syncthreads();
  for (int off = 128; off > 0; off >>= 1) {
    if (t < off) red[t] += red[t + off];
    __syncthreads();
  }
  if (t == 0) loss_part[blockIdx.x] = (double)red[0];
}

// ---------- scalars ----------
__global__ __launch_bounds__(256) void k_scalars(const int* __restrict__ counts,
                                                 const double* __restrict__ scal,
                                                 const double* __restrict__ loss_part,
                                                 float* __restrict__ out1,
                                                 float* __restrict__ out2,
                                                 float* __restrict__ out4) {
  __shared__ double r1[256], r2[256], r3[256];
  int t = threadIdx.x;
  double csum = scal[1];
  double e1 = 0.0, e2 = 0.0, lsum = 0.0;
  for (int i = t; i < NCODE; i += 256) {
    double c = (double)counts[i];
    double p = c / csum;
    e1 += p * log(p + 1e-10);
    double a = c / (double)BATCH;
    e2 += a * log(a + 1e-10);
  }
  for (int i = t; i < NLOSSBLK; i += 256) lsum += loss_part[i];
  r1[t] = e1; r2[t] = e2; r3[t] = lsum;
  __syncthreads();
  for (int off = 128; off > 0; off >>= 1) {
    if (t < off) { r1[t] += r1[t+off]; r2[t] += r2[t+off]; r3[t] += r3[t+off]; }
    __syncthreads();
  }
  if (t == 0) {
    double entropy = -r1[0];
    double maxent = log((double)NCODE);
    double div = (maxent - entropy) / maxent;
    double mse = r3[0] / ((double)BATCH * (double)DIM);
    double vq = 0.3 * mse + mse + 0.001 * div;
    double perp = exp(-r2[0]);
    *out1 = (float)vq;
    *out2 = (float)perp;
    *out4 = (float)div;
  }
}

extern "C" void kernel_launch(void* const* d_in, const int* in_sizes, int n_in,
                              void* d_out, int out_size, void* d_ws, size_t ws_size,
                              hipStream_t stream) {
  const float* z   = (const float*)d_in[0];
  const float* emb = (const float*)d_in[1];
  const float* cs  = (const float*)d_in[2];
  const float* ea  = (const float*)d_in[3];

  float* out  = (float*)d_out;
  float* out0 = out;                    // z_q_st        [B*D]
  float* out1 = out + 16777216;         // vq_loss       [1]
  float* out2 = out + 16777217;         // perplexity    [1]
  float* out3 = out + 16777218;         // indices       [B]
  float* out4 = out + 16809986;         // diversity     [1]
  float* out5 = out + 16809987;         // new_embedding [K*D]
  float* out6 = out + 21004291;         // new_cluster   [K]
  float* out7 = out + 21012483;         // final_embed_avg [K*D]

  char* ws = (char*)d_ws;
  double* scal      = (double*)(ws + OFF_SCAL);
  int*    cnt       = (int*)   (ws + OFF_CNT);
  int*    counts    = (int*)   (ws + OFF_COUNTS);
  float*  er        = (float*) (ws + OFF_ER);
  int*    idxs      = (int*)   (ws + OFF_IDX);
  double* loss_part = (double*)(ws + OFF_LOSS);
  int*    frow      = (int*)   (ws + OFF_FROW);
  int*    nft       = (int*)   (ws + OFF_NFT);
  int*    ftile     = (int*)   (ws + OFF_FTILE);
  float*  rval      = (float*) (ws + OFF_RVAL);
  int*    ridx      = (int*)   (ws + OFF_RIDX);
  _Float16* eh      = (_Float16*)(ws + OFF_EH);

  // overlays:
  //  zh (fp16 z) on out5/out7 (dead until k_embed writes them)
  //  coarse candidates c1v/c2v/c1i on out0[0 .. 6291456)
  //  bucket structures on out0 tail [13500000 ..) — k_gather (which rewrites
  //  out0) runs after k_embed has consumed them
  _Float16* zh5 = (_Float16*)out5;
  _Float16* zh7 = (_Float16*)out7;
  float* c1v = out0;
  float* c2v = out0 + (size_t)64 * BATCH;
  int*   c1i = (int*)(out0 + (size_t)128 * BATCH);
  int*   offs   = (int*)(out0 + 13500000);   // [NCODE+1]
  int*   curs   = offs + NCODE + 64;         // [NCODE]
  int*   bucket = curs + NCODE;              // [BATCH]

  hipMemsetAsync(ws, 0, OFF_ER, stream);  // scal, cnt, counts

  k_prep_e<<<NCODE / 4, 256, 0, stream>>>(emb, er, eh);
  k_prep_z<<<8192, 256, 0, stream>>>(z, zh5, zh7);
  k_coarse<<<dim3(BATCH / 128, NCODE / 128), 256, 0, stream>>>(eh, zh5, zh7, c1v, c2v, c1i);
  k_combine<<<BATCH / 256, 256, 0, stream>>>(c1v, c2v, c1i, idxs, out3, cnt, frow, nft, ftile);
  k_refine<<<MAXFLAG, 256, 0, stream>>>(z, emb, er, cnt, frow, nft, ftile, rval, ridx);
  k_merge<<<MAXFLAG / 256, 256, 0, stream>>>(cnt, frow, nft, rval, ridx, idxs, out3);

  k_count<<<BATCH / 256, 256, 0, stream>>>(idxs, counts);
  k_cluster<<<NCODE / 256, 256, 0, stream>>>(cs, counts, out6, scal);
  k_prefix<<<1, 256, 0, stream>>>(counts, offs, curs);
  k_bucket<<<BATCH / 256, 256, 0, stream>>>(idxs, curs, bucket);
  k_embed<<<NCODE, 128, 0, stream>>>(z, ea, offs, bucket, out6, scal, out5, out7);

  k_gather<<<NLOSSBLK, 256, 0, stream>>>(z, emb, idxs, out0, loss_part);
  k_scalars<<<1, 256, 0, stream>>>(counts, scal, loss_part, out1, out2, out4);
}

// Round 4
// 851.143 us; speedup vs baseline: 5.9539x; 1.0253x over previous
//
#include <hip/hip_runtime.h>
#include <math.h>

#define BATCH 32768
#define DIM   512
#define NCODE 8192
#define DECAYF 0.995f
#define OMDF   0.005f
#define EPSF   1e-8f
#define MARGIN 8e-3f
#define MAXFLAG 2048
#define MAXTILE 12

typedef _Float16 half8 __attribute__((ext_vector_type(8)));
typedef _Float16 half4 __attribute__((ext_vector_type(4)));
typedef float f32x4 __attribute__((ext_vector_type(4)));

// ---------------- workspace layout (bytes) ----------------
#define OFF_SCAL   0        // double scal[8]: [0]=n_sum [1]=counts_sum
#define OFF_CNT    64       // int cnt
#define OFF_COUNTS 128      // int counts[NCODE]
#define OFF_ER     32896    // float er[NCODE]
#define OFF_IDX    65664    // int idxs[BATCH]
#define OFF_LOSS   196736   // double loss_part[4096]
#define OFF_FROW   229504   // int frow[MAXFLAG]
#define OFF_NFT    237696   // int nft[MAXFLAG]
#define OFF_FTILE  245888   // int ftile[MAXFLAG*MAXTILE]
#define OFF_RVAL   344192   // float rval[MAXFLAG*MAXTILE]
#define OFF_RIDX   442496   // int ridx[MAXFLAG*MAXTILE]
#define OFF_EH     540800   // _Float16 eh[NCODE*DIM]  (8 MB)
#define NLOSSBLK   4096

__device__ inline void atomAddD(double* p, double v){ unsafeAtomicAdd(p, v); }

__device__ inline void async_cp16(const _Float16* g, _Float16* l) {
  __builtin_amdgcn_global_load_lds(
      (const __attribute__((address_space(1))) unsigned int*)g,
      (__attribute__((address_space(3))) unsigned int*)l, 16, 0, 0);
}

// ---------- prep: er[k]=1/(||e_k||+eps), eh = fp16(e*er) ----------
__global__ __launch_bounds__(256) void k_prep_e(const float* __restrict__ emb,
                                                float* __restrict__ er,
                                                _Float16* __restrict__ eh) {
  int row = blockIdx.x * 4 + (threadIdx.x >> 6);
  int l = threadIdx.x & 63;
  const float4* p = (const float4*)(emb + (size_t)row * DIM);
  float4 a = p[l], b = p[l + 64];
  float s = a.x*a.x + a.y*a.y + a.z*a.z + a.w*a.w
          + b.x*b.x + b.y*b.y + b.z*b.z + b.w*b.w;
  #pragma unroll
  for (int off = 32; off > 0; off >>= 1) s += __shfl_down(s, off);
  s = __shfl(s, 0);
  float inv = 1.0f / (sqrtf(s) + EPSF);
  if (l == 0) er[row] = inv;
  half4 ha = { (_Float16)(a.x*inv), (_Float16)(a.y*inv), (_Float16)(a.z*inv), (_Float16)(a.w*inv) };
  half4 hb = { (_Float16)(b.x*inv), (_Float16)(b.y*inv), (_Float16)(b.z*inv), (_Float16)(b.w*inv) };
  *(half4*)(eh + (size_t)row * DIM + l * 4) = ha;
  *(half4*)(eh + (size_t)row * DIM + 256 + l * 4) = hb;
}

// ---------- prep: zh = fp16(z) split across out5/out7 regions ----------
__global__ __launch_bounds__(256) void k_prep_z(const float* __restrict__ z,
                                                _Float16* __restrict__ z5,
                                                _Float16* __restrict__ z7) {
  size_t base = ((size_t)blockIdx.x * 256 + threadIdx.x) * 8;
  const float4* zp = (const float4*)(z + base);
  float4 a = zp[0], b = zp[1];
  half8 h = { (_Float16)a.x, (_Float16)a.y, (_Float16)a.z, (_Float16)a.w,
              (_Float16)b.x, (_Float16)b.y, (_Float16)b.z, (_Float16)b.w };
  _Float16* dst = (base < (size_t)16384 * 512) ? (z5 + base)
                                               : (z7 + (base - (size_t)16384 * 512));
  *(half8*)dst = h;
}

// ---------- coarse fp16 MFMA GEMM + per-row top-2 per 128-col tile ----------
// LDS layout XOR-swizzled so ds_read_b128 fragment reads are conflict-free:
// slot(R_local,Q) = R_local*4 + (Q ^ ((R_local>>1)&3))  [16B units]
// global_load_lds writes lane l -> slot l, so lane l fetches
// (r = l>>2, kq = (l&3)^((l>>3)&3)) from global.
__global__ __launch_bounds__(256) void k_coarse(const _Float16* __restrict__ eh,
                                                const _Float16* __restrict__ z5,
                                                const _Float16* __restrict__ z7,
                                                float* __restrict__ c1v,
                                                float* __restrict__ c2v,
                                                int* __restrict__ c1i) {
  __shared__ _Float16 As[4096];  // 128 rows x 32 k (swizzled)
  __shared__ _Float16 Bs[4096];  // 128 codes x 32 k (swizzled)
  __shared__ float ev1[2][128];
  __shared__ float ev2[2][128];
  __shared__ int   ei1[2][128];

  const int t = threadIdx.x, w = t >> 6, lane = t & 63;
  const int quad = lane >> 4, c16 = lane & 15;
  const int row0 = blockIdx.x * 128;
  const int by = blockIdx.y, col0 = by * 128;
  const int m0 = (w & 1) * 64, n0 = (w >> 1) * 64;
  const _Float16* zbase = (row0 < 16384) ? z5 : (z7 - (size_t)16384 * 512);

  const int kq = (lane & 3) ^ ((lane >> 3) & 3);   // swizzled k-quad this lane fetches
  const _Float16* ga[2]; const _Float16* gb[2];
  _Float16* la[2]; _Float16* lb[2];
  #pragma unroll
  for (int c = 0; c < 2; c++) {
    int r = (c * 4 + w) * 16 + (lane >> 2);
    ga[c] = zbase + (size_t)(row0 + r) * 512 + kq * 8;
    gb[c] = eh + (size_t)(col0 + r) * 512 + kq * 8;
    la[c] = As + (c * 4 + w) * 512;
    lb[c] = Bs + (c * 4 + w) * 512;
  }

  f32x4 acc[4][4];
  #pragma unroll
  for (int i = 0; i < 4; i++)
    #pragma unroll
    for (int j = 0; j < 4; j++) { acc[i][j][0]=0.f; acc[i][j][1]=0.f; acc[i][j][2]=0.f; acc[i][j][3]=0.f; }

  // fragment read offsets (halfs): group g = (m0>>4)+i, slot = c16*4 + (quad ^ ((c16>>1)&3))
  const int sw = (c16 * 4 + (quad ^ ((c16 >> 1) & 3))) * 8;
  int offA[4], offB[4];
  #pragma unroll
  for (int i = 0; i < 4; i++) offA[i] = ((m0 >> 4) + i) * 512 + sw;
  #pragma unroll
  for (int j = 0; j < 4; j++) offB[j] = ((n0 >> 4) + j) * 512 + sw;

  for (int kk = 0; kk < 16; kk++) {
    #pragma unroll
    for (int c = 0; c < 2; c++) {
      async_cp16(ga[c], la[c]); ga[c] += 32;
      async_cp16(gb[c], lb[c]); gb[c] += 32;
    }
    __syncthreads();
    half8 af[4], bf[4];
    #pragma unroll
    for (int i = 0; i < 4; i++) af[i] = *(const half8*)(As + offA[i]);
    #pragma unroll
    for (int j = 0; j < 4; j++) bf[j] = *(const half8*)(Bs + offB[j]);
    #pragma unroll
    for (int i = 0; i < 4; i++)
      #pragma unroll
      for (int j = 0; j < 4; j++)
        acc[i][j] = __builtin_amdgcn_mfma_f32_16x16x32_f16(af[i], bf[j], acc[i][j], 0, 0, 0);
    __syncthreads();
  }

  // epilogue: per-row top-2 over this block's 128 cols
  const int h = w >> 1;
  #pragma unroll
  for (int i = 0; i < 4; i++) {
    #pragma unroll
    for (int r = 0; r < 4; r++) {
      float v1 = acc[i][0][r];
      int   i1 = col0 + n0 + c16;
      float v2 = -3.0e38f;
      #pragma unroll
      for (int j = 1; j < 4; j++) {
        float v = acc[i][j][r];
        int ix = col0 + n0 + j * 16 + c16;
        if (v > v1) { v2 = fmaxf(v2, v1); v1 = v; i1 = ix; }
        else        { v2 = fmaxf(v2, v); }
      }
      #pragma unroll
      for (int m = 1; m < 16; m <<= 1) {
        float o1 = __shfl_xor(v1, m);
        float o2 = __shfl_xor(v2, m);
        int   oi = __shfl_xor(i1, m);
        if (o1 > v1 || (o1 == v1 && oi < i1)) { v2 = fmaxf(v1, o2); v1 = o1; i1 = oi; }
        else                                  { v2 = fmaxf(v2, o1); }
      }
      if (c16 == 0) {
        int rl = (w & 1) * 64 + i * 16 + quad * 4 + r;
        ev1[h][rl] = v1; ev2[h][rl] = v2; ei1[h][rl] = i1;
      }
    }
  }
  __syncthreads();
  if (t < 128) {
    float a1 = ev1[0][t], a2 = ev2[0][t]; int ai = ei1[0][t];
    float b1 = ev1[1][t], b2 = ev2[1][t]; int bi = ei1[1][t];
    float v1, v2; int i1;
    if (b1 > a1 || (b1 == a1 && bi < ai)) { v1 = b1; i1 = bi; v2 = fmaxf(a1, b2); }
    else                                  { v1 = a1; i1 = ai; v2 = fmaxf(a2, b1); }
    size_t o = (size_t)by * BATCH + row0 + t;
    c1v[o] = v1; c2v[o] = v2; c1i[o] = i1;
  }
}

// ---------- combine 64 tiles/row, margin test, flag list ----------
__global__ __launch_bounds__(256) void k_combine(const float* __restrict__ c1v,
                                                 const float* __restrict__ c2v,
                                                 const int* __restrict__ c1i,
                                                 int* __restrict__ idxs,
                                                 float* __restrict__ out3,
                                                 int* __restrict__ cnt,
                                                 int* __restrict__ frow,
                                                 int* __restrict__ nft,
                                                 int* __restrict__ ftile) {
  int row = blockIdx.x * 256 + threadIdx.x;
  float v1 = -3.0e38f, v2 = -3.0e38f; int i1 = 0;
  for (int ti = 0; ti < 64; ti++) {
    size_t o = (size_t)ti * BATCH + row;
    float a = c1v[o]; float a2 = c2v[o]; int ai = c1i[o];
    if (a > v1 || (a == v1 && ai < i1)) { v2 = fmaxf(v1, a2); v1 = a; i1 = ai; }
    else                                { v2 = fmaxf(v2, a); }
  }
  idxs[row] = i1;
  out3[row] = (float)i1;
  if (v1 - v2 < MARGIN) {
    int fid = atomicAdd(cnt, 1);
    if (fid < MAXFLAG) {
      frow[fid] = row;
      int jj = 0;
      for (int ti = 0; ti < 64; ti++) {
        if (c1v[(size_t)ti * BATCH + row] >= v1 - MARGIN && jj < MAXTILE)
          ftile[fid * MAXTILE + jj++] = ti;
      }
      nft[fid] = jj;
    }
  }
}

// ---------- exact fp32 refine of qualifying tiles for flagged rows ----------
__global__ __launch_bounds__(256) void k_refine(const float* __restrict__ z,
                                                const float* __restrict__ emb,
                                                const float* __restrict__ er,
                                                const int* __restrict__ cnt,
                                                const int* __restrict__ frow,
                                                const int* __restrict__ nft,
                                                const int* __restrict__ ftile,
                                                float* __restrict__ rval,
                                                int* __restrict__ ridx) {
  __shared__ float zl[512];
  __shared__ float rv[128];
  __shared__ int   ri[128];
  int fid = blockIdx.x;
  int m = cnt[0]; if (m > MAXFLAG) m = MAXFLAG;
  if (fid >= m) return;
  int t = threadIdx.x;
  int row = frow[fid];
  if (t < 128) ((float4*)zl)[t] = *(const float4*)(z + (size_t)row * 512 + t * 4);
  __syncthreads();
  int n = nft[fid];
  for (int jj = 0; jj < n; jj++) {
    int ti = ftile[fid * MAXTILE + jj];
    if (t < 128) {
      int code = ti * 128 + t;
      const float4* ep = (const float4*)(emb + (size_t)code * 512);
      const float4* zp = (const float4*)zl;
      float a0 = 0.f, a1 = 0.f, a2 = 0.f, a3 = 0.f;
      #pragma unroll 8
      for (int d = 0; d < 128; d++) {
        float4 e4 = ep[d]; float4 z4 = zp[d];
        a0 = fmaf(e4.x, z4.x, a0); a1 = fmaf(e4.y, z4.y, a1);
        a2 = fmaf(e4.z, z4.z, a2); a3 = fmaf(e4.w, z4.w, a3);
      }
      rv[t] = ((a0 + a1) + (a2 + a3)) * er[code];
      ri[t] = code;
    }
    __syncthreads();
    for (int off = 64; off > 0; off >>= 1) {
      if (t < off) {
        if (rv[t + off] > rv[t] || (rv[t + off] == rv[t] && ri[t + off] < ri[t])) {
          rv[t] = rv[t + off]; ri[t] = ri[t + off];
        }
      }
      __syncthreads();
    }
    if (t == 0) { rval[fid * MAXTILE + jj] = rv[0]; ridx[fid * MAXTILE + jj] = ri[0]; }
    __syncthreads();
  }
}

// ---------- merge refine results -> final index for flagged rows ----------
__global__ __launch_bounds__(256) void k_merge(const int* __restrict__ cnt,
                                               const int* __restrict__ frow,
                                               const int* __restrict__ nft,
                                               const float* __restrict__ rval,
                                               const int* __restrict__ ridx,
                                               int* __restrict__ idxs,
                                               float* __restrict__ out3) {
  int fid = blockIdx.x * 256 + threadIdx.x;
  int m = cnt[0]; if (m > MAXFLAG) m = MAXFLAG;
  if (fid >= m) return;
  int n = nft[fid];
  float bv = rval[fid * MAXTILE]; int bi = ridx[fid * MAXTILE];
  for (int jj = 1; jj < n; jj++) {
    float v = rval[fid * MAXTILE + jj]; int ix = ridx[fid * MAXTILE + jj];
    if (v > bv || (v == bv && ix < bi)) { bv = v; bi = ix; }
  }
  int row = frow[fid];
  idxs[row] = bi;
  out3[row] = (float)bi;
}

// ---------- counts from final indices (32768 int atomics) ----------
__global__ __launch_bounds__(256) void k_count(const int* __restrict__ idxs,
                                               int* __restrict__ counts) {
  int row = blockIdx.x * 256 + threadIdx.x;
  atomicAdd(&counts[idxs[row]], 1);
}

// ---------- exclusive prefix sum of counts -> offs, curs ----------
__global__ __launch_bounds__(256) void k_prefix(const int* __restrict__ counts,
                                                int* __restrict__ offs,
                                                int* __restrict__ curs) {
  __shared__ int ls[256];
  int t = threadIdx.x;
  int base = t * 32;
  int local[32];
  int s = 0;
  #pragma unroll
  for (int i = 0; i < 32; i++) { local[i] = s; s += counts[base + i]; }
  ls[t] = s;
  __syncthreads();
  for (int off = 1; off < 256; off <<= 1) {
    int add = (t >= off) ? ls[t - off] : 0;
    __syncthreads();
    ls[t] += add;
    __syncthreads();
  }
  int pre = (t == 0) ? 0 : ls[t - 1];
  #pragma unroll
  for (int i = 0; i < 32; i++) {
    int o = pre + local[i];
    offs[base + i] = o;
    curs[base + i] = o;
  }
  if (t == 255) offs[NCODE] = pre + s;
}

// ---------- scatter row ids into per-code buckets ----------
__global__ __launch_bounds__(256) void k_bucket(const int* __restrict__ idxs,
                                                int* __restrict__ curs,
                                                int* __restrict__ bucket) {
  int row = blockIdx.x * 256 + threadIdx.x;
  int idx = idxs[row];
  int pos = atomicAdd(&curs[idx], 1);
  bucket[pos] = row;
}

// ---------- cluster-size EMA + partial sums ----------
__global__ __launch_bounds__(256) void k_cluster(const float* __restrict__ cs,
                                                 const int* __restrict__ counts,
                                                 float* __restrict__ out6,
                                                 double* __restrict__ scal) {
  __shared__ double s1[256], s2[256];
  int t = threadIdx.x;
  int i = blockIdx.x * 256 + t;
  float cf = (float)counts[i];
  float ncs = DECAYF * cs[i] + OMDF * cf;
  out6[i] = ncs;
  s1[t] = (double)ncs;
  s2[t] = (double)cf;
  __syncthreads();
  for (int off = 128; off > 0; off >>= 1) {
    if (t < off) { s1[t] += s1[t + off]; s2[t] += s2[t + off]; }
    __syncthreads();
  }
  if (t == 0) { atomAddD(&scal[0], s1[0]); atomAddD(&scal[1], s2[0]); }
}

// ---------- embedding: bucket-sum + EMA + renormalize (no atomics) ----------
__global__ __launch_bounds__(128) void k_embed(const float* __restrict__ z,
                                               const float* __restrict__ ea,
                                               const int* __restrict__ offs,
                                               const int* __restrict__ bucket,
                                               const float* __restrict__ out6,
                                               const double* __restrict__ scal,
                                               float* __restrict__ out5,
                                               float* __restrict__ out7) {
  __shared__ float red[128];
  int k = blockIdx.x;
  int t = threadIdx.x;
  int beg = offs[k], end = offs[k + 1];
  float s0 = 0.f, s1 = 0.f, s2 = 0.f, s3 = 0.f;
  for (int j = beg; j < end; j++) {
    int r = bucket[j];
    float4 zv = *(const float4*)(z + (size_t)r * 512 + t * 4);
    s0 += zv.x; s1 += zv.y; s2 += zv.z; s3 += zv.w;
  }
  float n = (float)scal[0];
  float ncs = out6[k];
  float csn = (ncs + EPSF) / (n + (float)NCODE * EPSF) * n;
  size_t base = (size_t)k * 512 + t * 4;
  float4 eav = *(const float4*)(ea + base);
  float v[4];
  v[0] = (DECAYF * eav.x + OMDF * s0) / csn;
  v[1] = (DECAYF * eav.y + OMDF * s1) / csn;
  v[2] = (DECAYF * eav.z + OMDF * s2) / csn;
  v[3] = (DECAYF * eav.w + OMDF * s3) / csn;
  float ss = v[0]*v[0] + v[1]*v[1] + v[2]*v[2] + v[3]*v[3];
  red[t] = ss;
  __syncthreads();
  for (int off = 64; off > 0; off >>= 1) {
    if (t < off) red[t] += red[t + off];
    __syncthreads();
  }
  float inv = 1.0f / (sqrtf(red[0]) + EPSF);
  #pragma unroll
  for (int j = 0; j < 4; j++) {
    float nm = v[j] * inv;
    out5[base + j] = nm;
    out7[base + j] = nm * csn;
  }
}

// ---------- gather z_q -> out0 + MSE partials (no atomics) ----------
__global__ __launch_bounds__(256) void k_gather(
    const float* __restrict__ z, const float* __restrict__ emb,
    const int* __restrict__ idxs, float* __restrict__ out0,
    double* __restrict__ loss_part) {
  __shared__ float red[256];
  int t = threadIdx.x;
  int row = blockIdx.x * 8 + (t >> 5);
  int l = t & 31;
  int d0 = l * 16;
  int idx = idxs[row];
  const float4* zp = (const float4*)(z + (size_t)row * 512 + d0);
  const float4* ep = (const float4*)(emb + (size_t)idx * 512 + d0);
  float4* op = (float4*)(out0 + (size_t)row * 512 + d0);
  float ls = 0.f;
  #pragma unroll
  for (int q = 0; q < 4; q++) {
    float4 zv = zp[q];
    float4 ev = ep[q];
    op[q] = ev;  // z + (z_q - z) == z_q
    float dx = zv.x - ev.x, dy = zv.y - ev.y, dz = zv.z - ev.z, dw = zv.w - ev.w;
    ls += dx*dx + dy*dy + dz*dz + dw*dw;
  }
  red[t] = ls;
  __syncthreads();
  for (int off = 128; off > 0; off >>= 1) {
    if (t < off) red[t] += red[t + off];
    __syncthreads();
  }
  if (t == 0) loss_part[blockIdx.x] = (double)red[0];
}

// ---------- scalars ----------
__global__ __launch_bounds__(256) void k_scalars(const int* __restrict__ counts,
                                                 const double* __restrict__ scal,
                                                 const double* __restrict__ loss_part,
                                                 float* __restrict__ out1,
                                                 float* __restrict__ out2,
                                                 float* __restrict__ out4) {
  __shared__ double r1[256], r2[256], r3[256];
  int t = threadIdx.x;
  double csum = scal[1];
  double e1 = 0.0, e2 = 0.0, lsum = 0.0;
  for (int i = t; i < NCODE; i += 256) {
    double c = (double)counts[i];
    double p = c / csum;
    e1 += p * log(p + 1e-10);
    double a = c / (double)BATCH;
    e2 += a * log(a + 1e-10);
  }
  for (int i = t; i < NLOSSBLK; i += 256) lsum += loss_part[i];
  r1[t] = e1; r2[t] = e2; r3[t] = lsum;
  __syncthreads();
  for (int off = 128; off > 0; off >>= 1) {
    if (t < off) { r1[t] += r1[t+off]; r2[t] += r2[t+off]; r3[t] += r3[t+off]; }
    __syncthreads();
  }
  if (t == 0) {
    double entropy = -r1[0];
    double maxent = log((double)NCODE);
    double div = (maxent - entropy) / maxent;
    double mse = r3[0] / ((double)BATCH * (double)DIM);
    double vq = 0.3 * mse + mse + 0.001 * div;
    double perp = exp(-r2[0]);
    *out1 = (float)vq;
    *out2 = (float)perp;
    *out4 = (float)div;
  }
}

extern "C" void kernel_launch(void* const* d_in, const int* in_sizes, int n_in,
                              void* d_out, int out_size, void* d_ws, size_t ws_size,
                              hipStream_t stream) {
  const float* z   = (const float*)d_in[0];
  const float* emb = (const float*)d_in[1];
  const float* cs  = (const float*)d_in[2];
  const float* ea  = (const float*)d_in[3];

  float* out  = (float*)d_out;
  float* out0 = out;                    // z_q_st        [B*D]
  float* out1 = out + 16777216;         // vq_loss       [1]
  float* out2 = out + 16777217;         // perplexity    [1]
  float* out3 = out + 16777218;         // indices       [B]
  float* out4 = out + 16809986;         // diversity     [1]
  float* out5 = out + 16809987;         // new_embedding [K*D]
  float* out6 = out + 21004291;         // new_cluster   [K]
  float* out7 = out + 21012483;         // final_embed_avg [K*D]

  char* ws = (char*)d_ws;
  double* scal      = (double*)(ws + OFF_SCAL);
  int*    cnt       = (int*)   (ws + OFF_CNT);
  int*    counts    = (int*)   (ws + OFF_COUNTS);
  float*  er        = (float*) (ws + OFF_ER);
  int*    idxs      = (int*)   (ws + OFF_IDX);
  double* loss_part = (double*)(ws + OFF_LOSS);
  int*    frow      = (int*)   (ws + OFF_FROW);
  int*    nft       = (int*)   (ws + OFF_NFT);
  int*    ftile     = (int*)   (ws + OFF_FTILE);
  float*  rval      = (float*) (ws + OFF_RVAL);
  int*    ridx      = (int*)   (ws + OFF_RIDX);
  _Float16* eh      = (_Float16*)(ws + OFF_EH);

  // overlays:
  //  zh (fp16 z) on out5/out7 (dead until k_embed writes them)
  //  coarse candidates c1v/c2v/c1i on out0[0 .. 6291456)
  //  bucket structures on out0 tail [13500000 ..) — k_gather (which rewrites
  //  out0) runs after k_embed has consumed them
  _Float16* zh5 = (_Float16*)out5;
  _Float16* zh7 = (_Float16*)out7;
  float* c1v = out0;
  float* c2v = out0 + (size_t)64 * BATCH;
  int*   c1i = (int*)(out0 + (size_t)128 * BATCH);
  int*   offs   = (int*)(out0 + 13500000);   // [NCODE+1]
  int*   curs   = offs + NCODE + 64;         // [NCODE]
  int*   bucket = curs + NCODE;              // [BATCH]

  hipMemsetAsync(ws, 0, OFF_ER, stream);  // scal, cnt, counts

  k_prep_e<<<NCODE / 4, 256, 0, stream>>>(emb, er, eh);
  k_prep_z<<<8192, 256, 0, stream>>>(z, zh5, zh7);
  k_coarse<<<dim3(BATCH / 128, NCODE / 128), 256, 0, stream>>>(eh, zh5, zh7, c1v, c2v, c1i);
  k_combine<<<BATCH / 256, 256, 0, stream>>>(c1v, c2v, c1i, idxs, out3, cnt, frow, nft, ftile);
  k_refine<<<MAXFLAG, 256, 0, stream>>>(z, emb, er, cnt, frow, nft, ftile, rval, ridx);
  k_merge<<<MAXFLAG / 256, 256, 0, stream>>>(cnt, frow, nft, rval, ridx, idxs, out3);

  k_count<<<BATCH / 256, 256, 0, stream>>>(idxs, counts);
  k_cluster<<<NCODE / 256, 256, 0, stream>>>(cs, counts, out6, scal);
  k_prefix<<<1, 256, 0, stream>>>(counts, offs, curs);
  k_bucket<<<BATCH / 256, 256, 0, stream>>>(idxs, curs, bucket);
  k_embed<<<NCODE, 128, 0, stream>>>(z, ea, offs, bucket, out6, scal, out5, out7);

  k_gather<<<NLOSSBLK, 256, 0, stream>>>(z, emb, idxs, out0, loss_part);
  k_scalars<<<1, 256, 0, stream>>>(counts, scal, loss_part, out1, out2, out4);
}